// Round 15
// baseline (3949.348 us; speedup 1.0000x reference)
//
#include <hip/hip_runtime.h>

// Two-layer tanh RNN, persistent kernel (plain launch), MFMA bf16, epoch sync.
// Round-15 = round-12 (proven 3.86ms, MALL sc0sc1 fabric) + two consumer-side
// deltas (producer protocol byte-identical):
//  (1) K-half-matched epoch groups: consumer wave kh waits only on the 16
//      producers of its K-half (32B scan), starts loads as soon as its half
//      is ready. WAR checks split across the WG's two kh waves; combined at
//      the pre-write barrier they cover the full producer set (safe).
//  (2) pipelined double-buffered polling on critical waits (counted vmcnt,
//      rule-18 barriers, vmcnt(0) drain before exit - stray loads must land
//      before their VGPRs can be reused).
// XCD-local sc0 fabric (r13/r14) abandoned: two 600s hangs on unverified
// platform premise (XCC_ID placement / sc0 CU-to-CU visibility).
//
// 256 WGs x 512 thr: wg = layer*128 + rg4*32 + nb32.
//   rg4: 4 independent 16-row groups (batch-diagonal); nb32: 32-feat block.
//   Wave wv: fb=wv>>2, srcw=(wv>>1)&1, kh=wv&1. Weights 16 short8 = 64 VGPRs.
//   Ring matmul = 16 coherent loads in ONE batch + 16 MFMA.
// Flags: u16 epochs; group base (layer,rg4) = 32 slots; lo=nb32 0-15 (32B),
// hi=nb32 16-31 (32B).
//   L0 srcw1 wave kh @s: gL0.half(kh)>=s && gL1.half(kh)>=s-7 (WAR, fused)
//   L1 srcw1 wave kh @s: gL1.half(kh)>=s
//   L1 srcw0 wave kh @s: gL0.half(kh)>=s+1   (critical)
// Producer: LDS reduce -> tanh -> u16 ring stores (sc0 sc1) -> vmcnt(0) ->
// barrier -> tid0 epoch store -> f32 out stores (off critical path).

#define SEQ 512
#define BATCH 64
#define HID 1024
#define BH (BATCH * HID)
#define DEPTH 8

typedef __attribute__((ext_vector_type(8))) short short8;
typedef __attribute__((ext_vector_type(4))) float f32x4;
typedef __attribute__((ext_vector_type(4))) unsigned int u32x4;

__device__ __forceinline__ unsigned short f32_to_bf16_rne(float f) {
    unsigned int u = __float_as_uint(f);
    u += 0x7FFFu + ((u >> 16) & 1u);
    return (unsigned short)(u >> 16);
}

__device__ __forceinline__ short8 cvt8(float4 f0, float4 f1) {
    short8 w;
    w[0] = (short)f32_to_bf16_rne(f0.x);
    w[1] = (short)f32_to_bf16_rne(f0.y);
    w[2] = (short)f32_to_bf16_rne(f0.z);
    w[3] = (short)f32_to_bf16_rne(f0.w);
    w[4] = (short)f32_to_bf16_rne(f1.x);
    w[5] = (short)f32_to_bf16_rne(f1.y);
    w[6] = (short)f32_to_bf16_rne(f1.z);
    w[7] = (short)f32_to_bf16_rne(f1.w);
    return w;
}

// 16B device-coherent load (served at MALL), pipelineable; caller waits.
__device__ __forceinline__ void ld_cc16(short8& d, const unsigned short* p) {
    asm volatile("global_load_dwordx4 %0, %1, off sc0 sc1"
                 : "=v"(d) : "v"(p) : "memory");
}

__device__ __forceinline__ void vm_wait0() {
    asm volatile("s_waitcnt vmcnt(0)" ::: "memory");
    __builtin_amdgcn_sched_barrier(0);   // rule 18
}

// u16 device-coherent store (epochs, ring values)
__device__ __forceinline__ void st_cc16(unsigned short* p, unsigned v) {
    asm volatile("global_store_short %0, %1, off sc0 sc1"
                 :: "v"(p), "v"(v) : "memory");
}

__device__ __forceinline__ unsigned min_u16x4(u32x4 w, unsigned mn) {
    #pragma unroll
    for (int j = 0; j < 4; ++j) {
        unsigned lo = w[j] & 0xFFFFu, hi = w[j] >> 16;
        mn = mn < lo ? mn : lo;
        mn = mn < hi ? mn : hi;
    }
    return mn;
}

__device__ __forceinline__ void issue_half(u32x4& r0, u32x4& r1,
                                           const unsigned short* f) {
    asm volatile("global_load_dwordx4 %0, %1, off sc0 sc1"
                 : "=v"(r0) : "v"((const unsigned int*)f) : "memory");
    asm volatile("global_load_dwordx4 %0, %1, off sc0 sc1"
                 : "=v"(r1) : "v"((const unsigned int*)f + 4) : "memory");
}

// pipelined wait on one 32B half-group (16 u16 slots)
__device__ __forceinline__ void wait_half(const unsigned short* f, int target) {
    if (target <= 0) return;
    u32x4 a0, a1, b0, b1;
    issue_half(a0, a1, f);                       // batch A
    for (;;) {
        issue_half(b0, b1, f);                   // batch B
        asm volatile("s_waitcnt vmcnt(2)" ::: "memory");   // A done
        __builtin_amdgcn_sched_barrier(0);
        if ((int)min_u16x4(a1, min_u16x4(a0, 0xFFFFu)) >= target) break;
        __builtin_amdgcn_s_sleep(1);
        issue_half(a0, a1, f);                   // batch A again
        asm volatile("s_waitcnt vmcnt(2)" ::: "memory");   // B done
        __builtin_amdgcn_sched_barrier(0);
        if ((int)min_u16x4(b1, min_u16x4(b0, 0xFFFFu)) >= target) break;
        __builtin_amdgcn_s_sleep(1);
    }
    vm_wait0();   // drain strays: their dest VGPRs must not be live-reused
}

// pipelined fused wait: data half f0>=t0 AND WAR half f1>=t1
__device__ __forceinline__ void wait_half2(const unsigned short* f0, int t0,
                                           const unsigned short* f1, int t1) {
    if (t0 <= 0 && t1 <= 0) return;
    u32x4 a0, a1, a2, a3, b0, b1, b2, b3;
    issue_half(a0, a1, f0); issue_half(a2, a3, f1);
    for (;;) {
        issue_half(b0, b1, f0); issue_half(b2, b3, f1);
        asm volatile("s_waitcnt vmcnt(4)" ::: "memory");   // A done
        __builtin_amdgcn_sched_barrier(0);
        if ((int)min_u16x4(a1, min_u16x4(a0, 0xFFFFu)) >= t0 &&
            (int)min_u16x4(a3, min_u16x4(a2, 0xFFFFu)) >= t1) break;
        __builtin_amdgcn_s_sleep(1);
        issue_half(a0, a1, f0); issue_half(a2, a3, f1);
        asm volatile("s_waitcnt vmcnt(4)" ::: "memory");   // B done
        __builtin_amdgcn_sched_barrier(0);
        if ((int)min_u16x4(b1, min_u16x4(b0, 0xFFFFu)) >= t0 &&
            (int)min_u16x4(b3, min_u16x4(b2, 0xFFFFu)) >= t1) break;
        __builtin_amdgcn_s_sleep(1);
    }
    vm_wait0();
}

#define MFMA16(W, A, ACC) \
    ACC = __builtin_amdgcn_mfma_f32_16x16x32_bf16((W), (A), (ACC), 0, 0, 0)

// 16-ks ring matmul, ONE load batch (single MALL roundtrip) + 16 MFMA.
__device__ __forceinline__ void ring_mm16(const unsigned short* pr, size_t aoff,
                                          const short8* wreg, f32x4& acc) {
    short8 a[16];
    #pragma unroll
    for (int k = 0; k < 16; ++k)
        ld_cc16(a[k], pr + aoff + k * 32);
    vm_wait0();
    #pragma unroll
    for (int k = 0; k < 16; ++k)
        MFMA16(wreg[k], a[k], acc);
}

__global__ void cvt_f32_bf16(const float* __restrict__ src,
                             unsigned short* __restrict__ dst, int n4) {
    int i = blockIdx.x * blockDim.x + threadIdx.x;
    int stride = gridDim.x * blockDim.x;
    for (; i < n4; i += stride) {
        float4 f = ((const float4*)src)[i];
        ushort4 o;
        o.x = f32_to_bf16_rne(f.x);
        o.y = f32_to_bf16_rne(f.y);
        o.z = f32_to_bf16_rne(f.z);
        o.w = f32_to_bf16_rne(f.w);
        ((ushort4*)dst)[i] = o;
    }
}

__global__ void init_ws(uint4* __restrict__ p, int n16) {
    int i = blockIdx.x * blockDim.x + threadIdx.x;
    if (i < n16) p[i] = make_uint4(0u, 0u, 0u, 0u);
}

__global__ __launch_bounds__(512, 1) void rnn_mfma(
    const float* __restrict__ x,
    const unsigned short* __restrict__ xb, int use_xb,
    const float* __restrict__ Wi0, const float* __restrict__ bi0,
    const float* __restrict__ Wh0, const float* __restrict__ bh0,
    const float* __restrict__ Wi1, const float* __restrict__ bi1,
    const float* __restrict__ Wh1, const float* __restrict__ bh1,
    float* __restrict__ out,
    unsigned short* __restrict__ rings,
    unsigned short* __restrict__ flags)
{
    unsigned short* h1ring = rings;                  // [8][64][1024] bf16
    unsigned short* h2ring = rings + DEPTH * BH;

    const int tid   = threadIdx.x;
    const int wg    = blockIdx.x;        // 0..255
    const int layer = wg >> 7;           // 0/1
    const int rg4   = (wg >> 5) & 3;     // row-group: 16 batch rows
    const int nb32  = wg & 31;           // 32-feat block
    const int wv    = tid >> 6;          // 0..7
    const int lane  = tid & 63;
    const int fb    = wv >> 2;           // 16-feat half (0/1)
    const int srcw  = (wv >> 1) & 1;     // 0: first source, 1: recurrent
    const int kh    = wv & 1;            // K half

    // flag groups: base (layer,rg4) = 32 u16 slots; half h = slots h*16..+15
    unsigned short* gL0 = flags + (0 * 4 + rg4) * 64;
    unsigned short* gL1 = flags + (1 * 4 + rg4) * 64;
    unsigned short* ep_self = (layer ? gL1 : gL0) + nb32;
    const unsigned short* dataL0 = gL0 + kh * 16;   // 32B half this wave needs
    const unsigned short* dataL1 = gL1 + kh * 16;

    // ---- resident weights: 16 short8 = 64 VGPRs ----
    const float* Wsel = layer ? (srcw ? Wh1 : Wi1) : (srcw ? Wh0 : Wi0);
    const int f_w = nb32 * 32 + fb * 16 + (lane & 15);
    const int kcb = kh * 512 + (lane >> 4) * 8;
    short8 wreg[16];
    {
        const float* rw = Wsel + (size_t)f_w * HID + kcb;
        #pragma unroll
        for (int ks = 0; ks < 16; ++ks)
            wreg[ks] = cvt8(*(const float4*)(rw + ks * 32),
                            *(const float4*)(rw + ks * 32 + 4));
    }

    // activation (B-operand) address: one 16-row tile
    const int arow = rg4 * 16 + (lane & 15);
    const size_t aoff = (size_t)arow * HID + kcb;

    // reduce-phase constants: thread -> (feat 0..31, row 0..15)
    const int r_feat = tid & 31;
    const int r_row  = tid >> 5;
    const int gf     = nb32 * 32 + r_feat;
    const int grow   = rg4 * 16 + r_row;
    const float* biv = layer ? bi1 : bi0;
    const float* bhv = layer ? bh1 : bh0;
    const float biasv = biv[gf] + bhv[gf];
    const int rw_base = (r_feat >> 4) * 4;

    __shared__ float red[8][16][17];

    for (int s = 0; s < SEQ; ++s) {
        f32x4 acc = {0.f, 0.f, 0.f, 0.f};

        if (layer == 0 && srcw == 0) {
            // ---- x_s @ Wi0^T : static input, plain loads, no wait ----
            if (use_xb) {
                const unsigned short* px = xb + (size_t)s * BH + aoff;
                #pragma unroll
                for (int ks = 0; ks < 16; ++ks) {
                    short8 a = *(const short8*)(px + ks * 32);
                    MFMA16(wreg[ks], a, acc);
                }
            } else {
                const float* px = x + (size_t)s * BH + aoff;
                #pragma unroll
                for (int ks = 0; ks < 16; ++ks) {
                    short8 a = cvt8(*(const float4*)(px + ks * 32),
                                    *(const float4*)(px + ks * 32 + 4));
                    MFMA16(wreg[ks], a, acc);
                }
            }
        } else if (layer == 0) {
            // ---- h1[s-1] @ Wh0^T (critical; fused half-data + half-WAR) ----
            if (lane == 0) wait_half2(dataL0, s, dataL1, s - (DEPTH - 1));
            ring_mm16(h1ring + (size_t)((s - 1) & (DEPTH - 1)) * BH, aoff, wreg, acc);
        } else if (srcw == 1) {
            // ---- h2[s-1] @ Wh1^T ----
            if (lane == 0) wait_half(dataL1, s);
            ring_mm16(h2ring + (size_t)((s - 1) & (DEPTH - 1)) * BH, aoff, wreg, acc);
        } else {
            // ---- h1[s] @ Wi1^T (critical cross-layer) ----
            if (lane == 0) wait_half(dataL0, s + 1);
            ring_mm16(h1ring + (size_t)(s & (DEPTH - 1)) * BH, aoff, wreg, acc);
        }

        // ---- partials to LDS: red[wave][feat16][row16] ----
        #pragma unroll
        for (int r = 0; r < 4; ++r)
            red[wv][4 * (lane >> 4) + r][lane & 15] = acc[r];
        __syncthreads();

        // ---- reduce (4 partials) + tanh + u16 ring store: all 512 thr ----
        float v;
        {
            const int ff = r_feat & 15;
            v = red[rw_base][ff][r_row] + red[rw_base + 1][ff][r_row]
              + red[rw_base + 2][ff][r_row] + red[rw_base + 3][ff][r_row] + biasv;
            v = tanhf(v);
            unsigned short* ring_self =
                (layer ? h2ring : h1ring) + (size_t)(s & (DEPTH - 1)) * BH;
            st_cc16(ring_self + (size_t)grow * HID + gf, f32_to_bf16_rne(v));
        }

        asm volatile("s_waitcnt vmcnt(0)" ::: "memory");   // ring stores at MALL
        __builtin_amdgcn_sched_barrier(0);
        __syncthreads();                                   // all waves acked
        if (tid == 0)
            st_cc16(ep_self, (unsigned)(s + 1));

        // ---- f32 outputs (off critical path, after signal) ----
        if (layer == 1) {
            out[(size_t)s * BH + (size_t)grow * HID + gf] = v;
            if (s == SEQ - 1)
                out[(size_t)SEQ * BH + BH + (size_t)grow * HID + gf] = v;  // h_final[1]
        } else if (s == SEQ - 1) {
            out[(size_t)SEQ * BH + (size_t)grow * HID + gf] = v;           // h_final[0]
        }
    }
}

extern "C" void kernel_launch(void* const* d_in, const int* in_sizes, int n_in,
                              void* d_out, int out_size, void* d_ws, size_t ws_size,
                              hipStream_t stream) {
    const float* xp   = (const float*)d_in[0];
    const float* Wi0p = (const float*)d_in[1];
    const float* bi0p = (const float*)d_in[2];
    const float* Wh0p = (const float*)d_in[3];
    const float* bh0p = (const float*)d_in[4];
    const float* Wi1p = (const float*)d_in[5];
    const float* bi1p = (const float*)d_in[6];
    const float* Wh1p = (const float*)d_in[7];
    const float* bh1p = (const float*)d_in[8];
    float* outp = (float*)d_out;

    // ws layout: rings 2 MiB | flags 1 KiB (pad 4 KiB) | xb 64 MiB
    unsigned short* rings = (unsigned short*)d_ws;
    const size_t ring_bytes = (size_t)2 * DEPTH * BH * sizeof(unsigned short); // 2 MiB
    unsigned short* flags = (unsigned short*)((char*)d_ws + ring_bytes);
    const size_t flag_pad = 4096;
    unsigned short* xb = (unsigned short*)((char*)d_ws + ring_bytes + flag_pad);
    const size_t xb_bytes = (size_t)SEQ * BH * 2;                              // 64 MiB
    const int use_xb = (ws_size >= ring_bytes + flag_pad + xb_bytes) ? 1 : 0;

    {
        const int n16 = (int)((ring_bytes + flag_pad) / 16);
        init_ws<<<(n16 + 255) / 256, 256, 0, stream>>>((uint4*)d_ws, n16);
    }
    if (use_xb)
        cvt_f32_bf16<<<2048, 256, 0, stream>>>(xp, xb, SEQ * BH / 4);

    rnn_mfma<<<dim3(256), dim3(512), 0, stream>>>(
        xp, xb, use_xb,
        Wi0p, bi0p, Wh0p, bh0p, Wi1p, bi1p, Wh1p, bh1p,
        outp, rings, flags);
}